// Round 12
// baseline (331.526 us; speedup 1.0000x reference)
//
#include <hip/hip_runtime.h>
#include <hip/hip_bf16.h>
#include <math.h>

#define NN 20000
#define DD 64
#define HH 10
#define HDIM 640
#define NEG 0.2f
#define H1 1500
#define BKK 64       // gemm2 K-tile (32KB LDS dbuf -> 5 blocks/CU)

typedef _Float16 half8 __attribute__((ext_vector_type(8)));
typedef _Float16 half4v __attribute__((ext_vector_type(4)));
typedef float f32x4 __attribute__((ext_vector_type(4)));

// ---------------- both weight transposes in one launch ----------------
__global__ __launch_bounds__(256) void k_cvtB(const float* __restrict__ Wgcn,
                                              const float* __restrict__ Wg,
                                              _Float16* __restrict__ Wbt,
                                              _Float16* __restrict__ WgT)
{
    __shared__ float t[32][33];
    const int bx = blockIdx.x;
    int by = blockIdx.y;
    const float* W; _Float16* WT; int rows, cols;
    if (by < 20) { W = Wgcn; WT = Wbt; rows = HDIM; cols = HDIM; }
    else         { W = Wg;   WT = WgT; rows = DD;   cols = HDIM; by -= 20; }
    const int lx = threadIdx.x & 31, ly = threadIdx.x >> 5;
    #pragma unroll
    for (int i = ly; i < 32; i += 8)
        t[i][lx] = W[(size_t)(by * 32 + i) * cols + bx * 32 + lx];
    __syncthreads();
    #pragma unroll
    for (int j = ly; j < 32; j += 8)
        WT[(size_t)(bx * 32 + j) * rows + by * 32 + lx] = (_Float16)t[lx][j];
}

// ---------------- GEMM1 (MFMA fp16): xl = x @ W_gat, fused a_src/a_dst dots ----------------
__global__ __launch_bounds__(256) void k_gemm1(
    const float* __restrict__ x, const _Float16* __restrict__ WgT,
    const float* __restrict__ att_s, const float* __restrict__ att_d,
    _Float16* __restrict__ xl, float* __restrict__ aST, float* __restrict__ aDT)
{
    __shared__ _Float16 As[128][72];
    __shared__ _Float16 Bs[64][72];
    const int tid = threadIdx.x;
    const int m0 = blockIdx.x * 128;
    const int h  = blockIdx.y;
    const int n0 = h * 64;

    {
        const int row = tid >> 1, ch = (tid & 1) * 32;
        const int gr = m0 + row;
        if (gr < NN) {
            const float* xp = &x[(size_t)gr * DD + ch];
            #pragma unroll
            for (int i = 0; i < 8; ++i) {
                const float4 v = *(const float4*)&xp[i * 4];
                half4v o = {(_Float16)v.x, (_Float16)v.y, (_Float16)v.z, (_Float16)v.w};
                *(half4v*)&As[row][ch + i * 4] = o;
            }
        } else {
            const half8 z = {0, 0, 0, 0, 0, 0, 0, 0};
            #pragma unroll
            for (int i = 0; i < 4; ++i) *(half8*)&As[row][ch + i * 8] = z;
        }
    }
    {
        const int row = tid >> 2, part = (tid & 3) * 16;
        const _Float16* wp = &WgT[(size_t)(n0 + row) * DD + part];
        *(half8*)&Bs[row][part]     = *(const half8*)&wp[0];
        *(half8*)&Bs[row][part + 8] = *(const half8*)&wp[8];
    }
    __syncthreads();

    const int lane = tid & 63, wave = tid >> 6;
    const int l15 = lane & 15, quad = lane >> 4;
    f32x4 acc[2][4];
    #pragma unroll
    for (int r = 0; r < 2; ++r)
        #pragma unroll
        for (int c = 0; c < 4; ++c) acc[r][c] = (f32x4){0.f, 0.f, 0.f, 0.f};

    #pragma unroll
    for (int ks = 0; ks < 2; ++ks) {
        const half8 a0 = *(const half8*)&As[wave * 32 + l15][ks * 32 + quad * 8];
        const half8 a1 = *(const half8*)&As[wave * 32 + 16 + l15][ks * 32 + quad * 8];
        #pragma unroll
        for (int c = 0; c < 4; ++c) {
            const half8 b = *(const half8*)&Bs[c * 16 + l15][ks * 32 + quad * 8];
            acc[0][c] = __builtin_amdgcn_mfma_f32_16x16x32_f16(a0, b, acc[0][c], 0, 0, 0);
            acc[1][c] = __builtin_amdgcn_mfma_f32_16x16x32_f16(a1, b, acc[1][c], 0, 0, 0);
        }
    }

    float asv[4], adv[4];
    #pragma unroll
    for (int c = 0; c < 4; ++c) {
        asv[c] = att_s[h * DD + c * 16 + l15];
        adv[c] = att_d[h * DD + c * 16 + l15];
    }
    #pragma unroll
    for (int r = 0; r < 2; ++r) {
        float ps[4] = {0.f, 0.f, 0.f, 0.f}, pd[4] = {0.f, 0.f, 0.f, 0.f};
        #pragma unroll
        for (int c = 0; c < 4; ++c)
            #pragma unroll
            for (int g = 0; g < 4; ++g) {
                ps[g] = fmaf(acc[r][c][g], asv[c], ps[g]);
                pd[g] = fmaf(acc[r][c][g], adv[c], pd[g]);
            }
        #pragma unroll
        for (int m = 1; m <= 8; m <<= 1)
            #pragma unroll
            for (int g = 0; g < 4; ++g) {
                ps[g] += __shfl_xor(ps[g], m);
                pd[g] += __shfl_xor(pd[g], m);
            }
        #pragma unroll
        for (int c = 0; c < 4; ++c)
            #pragma unroll
            for (int g = 0; g < 4; ++g) {
                const int row = m0 + wave * 32 + r * 16 + quad * 4 + g;
                if (row < NN)
                    xl[(size_t)row * HDIM + n0 + c * 16 + l15] = (_Float16)acc[r][c][g];
            }
        if (l15 == 0)
            #pragma unroll
            for (int g = 0; g < 4; ++g) {
                const int row = m0 + wave * 32 + r * 16 + quad * 4 + g;
                if (row < NN) {
                    aST[(size_t)h * NN + row] = ps[g];
                    aDT[(size_t)h * NN + row] = pd[g];
                }
            }
    }
}

// ---------------- CSR build ----------------
__global__ void k_count(const int* __restrict__ ei, int E, int* __restrict__ cnt)
{
    const int e = blockIdx.x * blockDim.x + threadIdx.x;
    if (e >= E + NN) return;
    const int d = (e < E) ? ei[E + e] : (e - E);
    atomicAdd(&cnt[d], 1);
}

__global__ __launch_bounds__(1024) void k_scan(const int* __restrict__ cnt,
                                               int* __restrict__ rowptr,
                                               float* __restrict__ dinv)
{
    __shared__ int sh[1024];
    const int t = threadIdx.x;
    const int CH = 20;
    const int base = t * CH;
    int loc[CH];
    int s = 0;
    #pragma unroll
    for (int i = 0; i < CH; ++i) {
        const int idx = base + i;
        const int c = (idx < NN) ? cnt[idx] : 0;
        loc[i] = s; s += c;
    }
    sh[t] = s; __syncthreads();
    for (int off = 1; off < 1024; off <<= 1) {
        const int v = (t >= off) ? sh[t - off] : 0;
        __syncthreads();
        sh[t] += v;
        __syncthreads();
    }
    const int prev = (t == 0) ? 0 : sh[t - 1];
    #pragma unroll
    for (int i = 0; i < CH; ++i) {
        const int idx = base + i;
        if (idx < NN) {
            rowptr[idx] = prev + loc[i];
            dinv[idx]   = rsqrtf((float)cnt[idx]);
        }
    }
    if (t == 1023) rowptr[NN] = sh[1023];
}

// ---------------- fill CSR only (weights computed inline in gathers) ----------------
__global__ void k_fill(const int* __restrict__ ei, int E,
                       const int* __restrict__ rowptr,
                       int* __restrict__ cursor, int* __restrict__ csr)
{
    const int e = blockIdx.x * blockDim.x + threadIdx.x;
    if (e >= E + NN) return;
    int s, d;
    if (e < E) { s = ei[e]; d = ei[E + e]; } else { s = d = e - E; }
    const int pos = atomicAdd(&cursor[d], 1);
    csr[rowptr[d] + pos] = s;
}

// ---------------- sliced gathers (v7: v4 structure, unroll-8 main loop) ----------------
// r11 lesson: gathers are LATENCY-bound (fma_mix halved VALUBusy, time flat).
// Unroll-8 halves wait-points per node (deg~17: 4.3 -> 2.2+tail) with 2x
// independent loads in flight per wait. fmaf form (compiler schedules loads).
__device__ __forceinline__ bool slice_map3(int bid, int& s, int& m)
{
    const int r = bid & 7, k = bid >> 3;
    if (k < 625) { s = r; m = k; return true; }
    s = 8 + (r >> 2);
    m = (r & 3) * 157 + (k - 625);
    return m < 625;
}

__device__ __forceinline__ float lrexp(float a)
{
    return __expf(fmaxf(a, NEG * a));   // lrelu == max(a, 0.2a)
}

__global__ __launch_bounds__(256) void k_gat_gather7(
    const int* __restrict__ rowptr, const int* __restrict__ csr,
    const float* __restrict__ aST, const float* __restrict__ aDT,
    const _Float16* __restrict__ xl, const float* __restrict__ b_gat,
    _Float16* __restrict__ x1)
{
    int s, m;
    if (!slice_map3(blockIdx.x, s, m)) return;
    const int wave = threadIdx.x >> 6, lane = threadIdx.x & 63;
    const int g = lane >> 3, l = lane & 7;
    const int n = m * 32 + wave * 8 + g;
    const int col = s * 64 + l * 8;
    const float* __restrict__ as = aST + (size_t)s * NN;
    const _Float16* __restrict__ xc = xl + col;
    const float ad = aDT[(size_t)s * NN + n];

    float acc[8];
    #pragma unroll
    for (int i = 0; i < 8; ++i) acc[i] = 0.f;
    float ws = 0.f;

    const int j0 = rowptr[n], j1 = rowptr[n + 1];
    int j = j0;
    for (; j + 7 < j1; j += 8) {
        int s_[8];
        #pragma unroll
        for (int q = 0; q < 8; ++q) s_[q] = csr[j + q];
        float w_[8];
        #pragma unroll
        for (int q = 0; q < 8; ++q) w_[q] = lrexp(as[s_[q]] + ad);
        half8 v_[8];
        #pragma unroll
        for (int q = 0; q < 8; ++q) v_[q] = *(const half8*)&xc[(size_t)s_[q] * HDIM];
        #pragma unroll
        for (int q = 0; q < 8; ++q) ws += w_[q];
        #pragma unroll
        for (int q = 0; q < 8; ++q)
            #pragma unroll
            for (int i = 0; i < 8; ++i)
                acc[i] = fmaf(w_[q], (float)v_[q][i], acc[i]);
    }
    for (; j + 3 < j1; j += 4) {
        int s_[4];
        #pragma unroll
        for (int q = 0; q < 4; ++q) s_[q] = csr[j + q];
        float w_[4];
        #pragma unroll
        for (int q = 0; q < 4; ++q) w_[q] = lrexp(as[s_[q]] + ad);
        half8 v_[4];
        #pragma unroll
        for (int q = 0; q < 4; ++q) v_[q] = *(const half8*)&xc[(size_t)s_[q] * HDIM];
        #pragma unroll
        for (int q = 0; q < 4; ++q) ws += w_[q];
        #pragma unroll
        for (int q = 0; q < 4; ++q)
            #pragma unroll
            for (int i = 0; i < 8; ++i)
                acc[i] = fmaf(w_[q], (float)v_[q][i], acc[i]);
    }
    for (; j < j1; ++j) {
        const int sA = csr[j];
        const float wA = lrexp(as[sA] + ad);
        ws += wA;
        const half8 vA = *(const half8*)&xc[(size_t)sA * HDIM];
        #pragma unroll
        for (int i = 0; i < 8; ++i) acc[i] = fmaf(wA, (float)vA[i], acc[i]);
    }

    const float rr = 1.f / (ws + 1e-16f);
    const float4 ba = *(const float4*)&b_gat[col];
    const float4 bb = *(const float4*)&b_gat[col + 4];
    const float bv[8] = {ba.x, ba.y, ba.z, ba.w, bb.x, bb.y, bb.z, bb.w};
    half8 o;
    #pragma unroll
    for (int i = 0; i < 8; ++i) {
        const float v = fmaf(acc[i], rr, bv[i]);
        o[i] = (_Float16)((v > 0.f) ? v : 0.f);
    }
    *(half8*)&x1[(size_t)n * HDIM + col] = o;
}

__global__ __launch_bounds__(256) void k_gcn_gather7(
    const int* __restrict__ rowptr, const int* __restrict__ csr,
    const float* __restrict__ dinv, const _Float16* __restrict__ x1,
    _Float16* __restrict__ t)
{
    int s, m;
    if (!slice_map3(blockIdx.x, s, m)) return;
    const int wave = threadIdx.x >> 6, lane = threadIdx.x & 63;
    const int g = lane >> 3, l = lane & 7;
    const int n = m * 32 + wave * 8 + g;
    const int col = s * 64 + l * 8;
    const _Float16* __restrict__ xc = x1 + col;
    const float dd = dinv[n];

    float acc[8];
    #pragma unroll
    for (int i = 0; i < 8; ++i) acc[i] = 0.f;

    const int j0 = rowptr[n], j1 = rowptr[n + 1];
    int j = j0;
    for (; j + 7 < j1; j += 8) {
        int s_[8];
        #pragma unroll
        for (int q = 0; q < 8; ++q) s_[q] = csr[j + q];
        float w_[8];
        #pragma unroll
        for (int q = 0; q < 8; ++q) w_[q] = dinv[s_[q]];
        half8 v_[8];
        #pragma unroll
        for (int q = 0; q < 8; ++q) v_[q] = *(const half8*)&xc[(size_t)s_[q] * HDIM];
        #pragma unroll
        for (int q = 0; q < 8; ++q)
            #pragma unroll
            for (int i = 0; i < 8; ++i)
                acc[i] = fmaf(w_[q], (float)v_[q][i], acc[i]);
    }
    for (; j + 3 < j1; j += 4) {
        int s_[4];
        #pragma unroll
        for (int q = 0; q < 4; ++q) s_[q] = csr[j + q];
        float w_[4];
        #pragma unroll
        for (int q = 0; q < 4; ++q) w_[q] = dinv[s_[q]];
        half8 v_[4];
        #pragma unroll
        for (int q = 0; q < 4; ++q) v_[q] = *(const half8*)&xc[(size_t)s_[q] * HDIM];
        #pragma unroll
        for (int q = 0; q < 4; ++q)
            #pragma unroll
            for (int i = 0; i < 8; ++i)
                acc[i] = fmaf(w_[q], (float)v_[q][i], acc[i]);
    }
    for (; j < j1; ++j) {
        const int sA = csr[j];
        const float wA = dinv[sA];
        const half8 vA = *(const half8*)&xc[(size_t)sA * HDIM];
        #pragma unroll
        for (int i = 0; i < 8; ++i) acc[i] = fmaf(wA, (float)vA[i], acc[i]);
    }

    half8 o;
    #pragma unroll
    for (int i = 0; i < 8; ++i) o[i] = (_Float16)(acc[i] * dd);
    *(half8*)&t[(size_t)n * HDIM + col] = o;
}

// ---------------- GEMM2 v5: BKK=64 dbuf + counted vmcnt + sched_barrier fences ----------------
__global__ __launch_bounds__(256) void k_gemm2(const _Float16* __restrict__ X,
                                               const _Float16* __restrict__ Wbt,
                                               const float* __restrict__ b_gcn,
                                               float* __restrict__ pmax,
                                               float* __restrict__ psum)
{
    __shared__ _Float16 Bs[2][128 * BKK];
    const int bid = blockIdx.x;
    const int r = bid & 7, q = bid >> 3;
    const int strip = (q / 5) * 8 + r;   // M-strip (0..156)
    const int nt = q % 5;                // N-tile (0..4)
    if (strip >= 157) return;

    const int tid = threadIdx.x;
    const int lane = tid & 63, wave = tid >> 6;
    const int l15 = lane & 15, quad = lane >> 4;
    const int m0 = strip * 128 + wave * 32;
    const int n0 = nt * 128;

    f32x4 acc[2][8];
    #pragma unroll
    for (int rr = 0; rr < 2; ++rr)
        #pragma unroll
        for (int c = 0; c < 8; ++c) acc[rr][c] = (f32x4){0.f, 0.f, 0.f, 0.f};

    const _Float16* a0p = &X[(size_t)(m0 + l15) * HDIM + quad * 8];
    const _Float16* a1p = a0p + (size_t)16 * HDIM;
    const int srow = wave * 8 + (lane >> 3);   // stage row base (0..31)
    const int sck  = lane & 7;                 // linear LDS chunk

#define STAGE4(buf, kb)                                                          \
    {                                                                            \
        _Pragma("unroll")                                                        \
        for (int i = 0; i < 4; ++i) {                                            \
            const int rw = i * 32 + srow;                                        \
            const int ck = sck ^ (rw & 7);                                       \
            const _Float16* src = &Wbt[(size_t)(n0 + rw) * HDIM + (kb) + ck * 8];\
            __builtin_amdgcn_global_load_lds(                                    \
                (const __attribute__((address_space(1))) void*)src,              \
                (__attribute__((address_space(3))) void*)&Bs[buf][((size_t)i * 256 + tid) * 8], \
                16, 0, 0);                                                       \
        }                                                                        \
    }

    STAGE4(0, 0);
    for (int it = 0; it < 10; ++it) {
        const int kb = it * BKK;
        half8 a0[2], a1[2];
        #pragma unroll
        for (int ks = 0; ks < 2; ++ks) {
            a0[ks] = *(const half8*)(a0p + kb + ks * 32);
            a1[ks] = *(const half8*)(a1p + kb + ks * 32);
        }
        if (it < 9) {
            STAGE4((it + 1) & 1, kb + BKK);
            // outstanding: stage(it)<=4 [oldest] + A(it)=4 + stage(it+1)=4
            asm volatile("s_waitcnt vmcnt(4)" ::: "memory");
        } else {
            asm volatile("s_waitcnt vmcnt(0)" ::: "memory");
        }
        __builtin_amdgcn_s_barrier();            // stage(it) visible to all waves
        __builtin_amdgcn_sched_barrier(0);       // fence: ds_reads must stay below
        const _Float16* Bsc = Bs[it & 1];
        #pragma unroll
        for (int ks = 0; ks < 2; ++ks) {
            #pragma unroll
            for (int c = 0; c < 8; ++c) {
                const int br = c * 16 + l15;
                const int ck = (ks * 4 + quad) ^ (br & 7);
                const half8 b = *(const half8*)&Bsc[(size_t)br * BKK + ck * 8];
                acc[0][c] = __builtin_amdgcn_mfma_f32_16x16x32_f16(a0[ks], b, acc[0][c], 0, 0, 0);
                acc[1][c] = __builtin_amdgcn_mfma_f32_16x16x32_f16(a1[ks], b, acc[1][c], 0, 0, 0);
            }
        }
        __builtin_amdgcn_sched_barrier(0);       // fence: ds_reads complete above
        __builtin_amdgcn_s_barrier();            // Bs[it&1] reads done before overwrite
        __builtin_amdgcn_sched_barrier(0);
    }
#undef STAGE4

    float lmax[8], lsum[8];
    #pragma unroll
    for (int c = 0; c < 8; ++c) { lmax[c] = 0.f; lsum[c] = 0.f; }
    #pragma unroll
    for (int c = 0; c < 8; ++c) {
        const float bb = b_gcn[n0 + c * 16 + l15];
        #pragma unroll
        for (int rr = 0; rr < 2; ++rr)
            #pragma unroll
            for (int g = 0; g < 4; ++g) {
                const int row = m0 + rr * 16 + quad * 4 + g;
                if (row < NN) {
                    float v = acc[rr][c][g] + bb;
                    v = (v > 0.f) ? v : 0.f;
                    lmax[c] = fmaxf(lmax[c], v);
                    lsum[c] += v;
                }
            }
    }
    float* redm = (float*)Bs;
    float* reds = redm + 128;
    if (tid < 128) { redm[tid] = 0.f; reds[tid] = 0.f; }
    __syncthreads();
    #pragma unroll
    for (int c = 0; c < 8; ++c) {
        const int col = c * 16 + l15;
        atomicMax((int*)&redm[col], __float_as_int(lmax[c]));
        atomicAdd(&reds[col], lsum[c]);
    }
    __syncthreads();
    if (tid < 128) {
        atomicMax((int*)&pmax[n0 + tid], __float_as_int(redm[tid]));
        atomicAdd(&psum[n0 + tid], reds[tid]);
    }
}

// ---------------- MLP layer 1 (split-K into hacc) ----------------
__global__ __launch_bounds__(256) void k_mlp1(const float* __restrict__ pmax,
                                              const float* __restrict__ psum,
                                              const float* __restrict__ W1,
                                              float* __restrict__ hacc)
{
    __shared__ float pl[80];
    const int t = threadIdx.x;
    const int i0 = blockIdx.y * 80;
    if (t < 80) {
        const int i = i0 + t;
        pl[t] = (i < HDIM) ? pmax[i] : psum[i - HDIM] * (1.0f / NN);
    }
    __syncthreads();
    const int j = blockIdx.x * 256 + t;
    if (j >= H1) return;
    float acc = 0.f;
    #pragma unroll 8
    for (int i = 0; i < 80; ++i)
        acc = fmaf(pl[i], W1[(size_t)(i0 + i) * H1 + j], acc);
    atomicAdd(&hacc[j], acc);
}

// ---------------- MLP layer 2 ----------------
__global__ __launch_bounds__(256) void k_mlp2(const float* __restrict__ hacc,
                                              const float* __restrict__ b1,
                                              const float* __restrict__ W2,
                                              const float* __restrict__ b2,
                                              float* __restrict__ out)
{
    __shared__ float hsh[H1];
    __shared__ float red[256];
    const int t = threadIdx.x;
    for (int i = t; i < H1; i += 256) {
        const float v = hacc[i] + b1[i];
        hsh[i] = (v > 0.f) ? v : 0.f;
    }
    __syncthreads();
    float acc[10];
    #pragma unroll
    for (int k = 0; k < 10; ++k) acc[k] = 0.f;
    for (int i = t; i < H1; i += 256) {
        const float h = hsh[i];
        #pragma unroll
        for (int k = 0; k < 10; ++k) acc[k] = fmaf(h, W2[i * 10 + k], acc[k]);
    }
    for (int k = 0; k < 10; ++k) {
        red[t] = acc[k]; __syncthreads();
        for (int s2 = 128; s2 > 0; s2 >>= 1) {
            if (t < s2) red[t] += red[t + s2];
            __syncthreads();
        }
        if (t == 0) out[k] = red[0] + b2[k];
        __syncthreads();
    }
}

// ---------------- launch ----------------
extern "C" void kernel_launch(void* const* d_in, const int* in_sizes, int n_in,
                              void* d_out, int out_size, void* d_ws, size_t ws_size,
                              hipStream_t stream)
{
    const float* x     = (const float*)d_in[0];
    const float* Wg    = (const float*)d_in[1];
    const float* att_s = (const float*)d_in[2];
    const float* att_d = (const float*)d_in[3];
    const float* b_gat = (const float*)d_in[4];
    const float* Wgcn  = (const float*)d_in[5];
    const float* b_gcn = (const float*)d_in[6];
    const float* W1    = (const float*)d_in[7];
    const float* b1    = (const float*)d_in[8];
    const float* W2    = (const float*)d_in[9];
    const float* b2    = (const float*)d_in[10];
    const int*   ei    = (const int*)d_in[11];
    const int E = in_sizes[11] / 2;
    const int EP = E + NN;
    float* out = (float*)d_out;

    char* wsp = (char*)d_ws;
    size_t off = 0;
    auto alc = [&](size_t b) { void* p = wsp + off; off += (b + 255) & ~(size_t)255; return p; };
    _Float16* bufA = (_Float16*)alc((size_t)NN * HDIM * 2);  // xl, later t
    _Float16* bufB = (_Float16*)alc((size_t)NN * HDIM * 2);  // x1
    float* aST    = (float*)alc((size_t)HH * NN * 4);        // [head][node]
    float* aDT    = (float*)alc((size_t)HH * NN * 4);        // [head][node]
    int*   rowptr = (int*)alc((size_t)(NN + 1) * 4);
    int*   csr    = (int*)alc((size_t)EP * 4);
    float* dinv   = (float*)alc((size_t)NN * 4);
    _Float16* Wbt = (_Float16*)alc((size_t)HDIM * HDIM * 2); // W_gcn^T fp16
    _Float16* WgT = (_Float16*)alc((size_t)HDIM * DD * 2);   // W_gat^T fp16 [640][64]
    // zero-initialized region (single memset): cnt | cursor | pmax | psum | hacc
    const size_t zoff = off;
    int*   cnt    = (int*)alc((size_t)NN * 4);
    int*   cursor = (int*)alc((size_t)NN * 4);
    float* pmax   = (float*)alc((size_t)HDIM * 4);
    float* psum   = (float*)alc((size_t)HDIM * 4);
    float* hacc   = (float*)alc((size_t)H1 * 4);
    const size_t zsize = off - zoff;

    hipMemsetAsync(cnt, 0, zsize, stream);

    dim3 gw(HDIM / 32, HDIM / 32 + DD / 32);
    k_cvtB<<<gw, 256, 0, stream>>>(Wgcn, Wg, Wbt, WgT);
    dim3 g1((NN + 127) / 128, HH);
    k_gemm1<<<g1, 256, 0, stream>>>(x, WgT, att_s, att_d, bufA, aST, aDT);
    k_count<<<(EP + 255) / 256, 256, 0, stream>>>(ei, E, cnt);
    k_scan<<<1, 1024, 0, stream>>>(cnt, rowptr, dinv);
    k_fill<<<(EP + 255) / 256, 256, 0, stream>>>(ei, E, rowptr, cursor, csr);
    const int GG = 6256;  // 8 XCD groups x 782 (625 pinned + 157 shared)
    k_gat_gather7<<<GG, 256, 0, stream>>>(rowptr, csr, aST, aDT, bufA, b_gat, bufB);
    k_gcn_gather7<<<GG, 256, 0, stream>>>(rowptr, csr, dinv, bufB, bufA);
    // 8 XCD groups x 100 (20 strips x 5 n-tiles; strips 157..159 guarded out)
    k_gemm2<<<800, 256, 0, stream>>>(bufA, Wbt, b_gcn, pmax, psum);
    dim3 gm1(6, 16);
    k_mlp1<<<gm1, 256, 0, stream>>>(pmax, psum, W1, hacc);
    k_mlp2<<<1, 256, 0, stream>>>(hacc, b1, W2, b2, out);
}

// Round 13
// 316.447 us; speedup vs baseline: 1.0477x; 1.0477x over previous
//
#include <hip/hip_runtime.h>
#include <hip/hip_bf16.h>
#include <math.h>

#define NN 20000
#define DD 64
#define HH 10
#define HDIM 640
#define NEG 0.2f
#define H1 1500
#define BKK 64       // gemm2 K-tile (32KB LDS dbuf -> 5 blocks/CU)

typedef _Float16 half8 __attribute__((ext_vector_type(8)));
typedef _Float16 half4v __attribute__((ext_vector_type(4)));
typedef float f32x4 __attribute__((ext_vector_type(4)));

// ---------------- prep: weight transposes (440 blocks) || degree count (1329) ----------------
__global__ __launch_bounds__(256) void k_prep(const float* __restrict__ Wgcn,
                                              const float* __restrict__ Wg,
                                              _Float16* __restrict__ Wbt,
                                              _Float16* __restrict__ WgT,
                                              const int* __restrict__ ei, int E,
                                              int* __restrict__ cnt)
{
    const int bid = blockIdx.x;
    if (bid < 440) {
        __shared__ float t[32][33];
        const int bx = bid % 20;
        int by = bid / 20;
        const float* W; _Float16* WT; int rows, cols;
        if (by < 20) { W = Wgcn; WT = Wbt; rows = HDIM; cols = HDIM; }
        else         { W = Wg;   WT = WgT; rows = DD;   cols = HDIM; by -= 20; }
        const int lx = threadIdx.x & 31, ly = threadIdx.x >> 5;
        #pragma unroll
        for (int i = ly; i < 32; i += 8)
            t[i][lx] = W[(size_t)(by * 32 + i) * cols + bx * 32 + lx];
        __syncthreads();
        #pragma unroll
        for (int j = ly; j < 32; j += 8)
            WT[(size_t)(bx * 32 + j) * rows + by * 32 + lx] = (_Float16)t[lx][j];
    } else {
        const int e = (bid - 440) * 256 + threadIdx.x;
        if (e >= E + NN) return;
        const int d = (e < E) ? ei[E + e] : (e - E);
        atomicAdd(&cnt[d], 1);
    }
}

// ---------------- scan (unchanged) ----------------
__global__ __launch_bounds__(1024) void k_scan(const int* __restrict__ cnt,
                                               int* __restrict__ rowptr,
                                               float* __restrict__ dinv)
{
    __shared__ int sh[1024];
    const int t = threadIdx.x;
    const int CH = 20;
    const int base = t * CH;
    int loc[CH];
    int s = 0;
    #pragma unroll
    for (int i = 0; i < CH; ++i) {
        const int idx = base + i;
        const int c = (idx < NN) ? cnt[idx] : 0;
        loc[i] = s; s += c;
    }
    sh[t] = s; __syncthreads();
    for (int off = 1; off < 1024; off <<= 1) {
        const int v = (t >= off) ? sh[t - off] : 0;
        __syncthreads();
        sh[t] += v;
        __syncthreads();
    }
    const int prev = (t == 0) ? 0 : sh[t - 1];
    #pragma unroll
    for (int i = 0; i < CH; ++i) {
        const int idx = base + i;
        if (idx < NN) {
            rowptr[idx] = prev + loc[i];
            dinv[idx]   = rsqrtf((float)cnt[idx]);
        }
    }
    if (t == 1023) rowptr[NN] = sh[1023];
}

// ---------------- big: GEMM1 (1570 blocks) || CSR fill (1329 blocks) ----------------
__global__ __launch_bounds__(256) void k_big(
    const float* __restrict__ x, const _Float16* __restrict__ WgT,
    const float* __restrict__ att_s, const float* __restrict__ att_d,
    _Float16* __restrict__ xl, float* __restrict__ aST, float* __restrict__ aDT,
    const int* __restrict__ ei, int E, const int* __restrict__ rowptr,
    int* __restrict__ cursor, int* __restrict__ csr)
{
    const int bid = blockIdx.x;
    if (bid >= 1570) {
        const int e = (bid - 1570) * 256 + threadIdx.x;
        if (e >= E + NN) return;
        int s, d;
        if (e < E) { s = ei[e]; d = ei[E + e]; } else { s = d = e - E; }
        const int pos = atomicAdd(&cursor[d], 1);
        csr[rowptr[d] + pos] = s;
        return;
    }

    __shared__ _Float16 As[128][72];
    __shared__ _Float16 Bs[64][72];
    const int tid = threadIdx.x;
    const int m0 = (bid % 157) * 128;
    const int h  = bid / 157;
    const int n0 = h * 64;

    {
        const int row = tid >> 1, ch = (tid & 1) * 32;
        const int gr = m0 + row;
        if (gr < NN) {
            const float* xp = &x[(size_t)gr * DD + ch];
            #pragma unroll
            for (int i = 0; i < 8; ++i) {
                const float4 v = *(const float4*)&xp[i * 4];
                half4v o = {(_Float16)v.x, (_Float16)v.y, (_Float16)v.z, (_Float16)v.w};
                *(half4v*)&As[row][ch + i * 4] = o;
            }
        } else {
            const half8 z = {0, 0, 0, 0, 0, 0, 0, 0};
            #pragma unroll
            for (int i = 0; i < 4; ++i) *(half8*)&As[row][ch + i * 8] = z;
        }
    }
    {
        const int row = tid >> 2, part = (tid & 3) * 16;
        const _Float16* wp = &WgT[(size_t)(n0 + row) * DD + part];
        *(half8*)&Bs[row][part]     = *(const half8*)&wp[0];
        *(half8*)&Bs[row][part + 8] = *(const half8*)&wp[8];
    }
    __syncthreads();

    const int lane = tid & 63, wave = tid >> 6;
    const int l15 = lane & 15, quad = lane >> 4;
    f32x4 acc[2][4];
    #pragma unroll
    for (int r = 0; r < 2; ++r)
        #pragma unroll
        for (int c = 0; c < 4; ++c) acc[r][c] = (f32x4){0.f, 0.f, 0.f, 0.f};

    #pragma unroll
    for (int ks = 0; ks < 2; ++ks) {
        const half8 a0 = *(const half8*)&As[wave * 32 + l15][ks * 32 + quad * 8];
        const half8 a1 = *(const half8*)&As[wave * 32 + 16 + l15][ks * 32 + quad * 8];
        #pragma unroll
        for (int c = 0; c < 4; ++c) {
            const half8 b = *(const half8*)&Bs[c * 16 + l15][ks * 32 + quad * 8];
            acc[0][c] = __builtin_amdgcn_mfma_f32_16x16x32_f16(a0, b, acc[0][c], 0, 0, 0);
            acc[1][c] = __builtin_amdgcn_mfma_f32_16x16x32_f16(a1, b, acc[1][c], 0, 0, 0);
        }
    }

    float asv[4], adv[4];
    #pragma unroll
    for (int c = 0; c < 4; ++c) {
        asv[c] = att_s[h * DD + c * 16 + l15];
        adv[c] = att_d[h * DD + c * 16 + l15];
    }
    #pragma unroll
    for (int r = 0; r < 2; ++r) {
        float ps[4] = {0.f, 0.f, 0.f, 0.f}, pd[4] = {0.f, 0.f, 0.f, 0.f};
        #pragma unroll
        for (int c = 0; c < 4; ++c)
            #pragma unroll
            for (int g = 0; g < 4; ++g) {
                ps[g] = fmaf(acc[r][c][g], asv[c], ps[g]);
                pd[g] = fmaf(acc[r][c][g], adv[c], pd[g]);
            }
        #pragma unroll
        for (int m = 1; m <= 8; m <<= 1)
            #pragma unroll
            for (int g = 0; g < 4; ++g) {
                ps[g] += __shfl_xor(ps[g], m);
                pd[g] += __shfl_xor(pd[g], m);
            }
        #pragma unroll
        for (int c = 0; c < 4; ++c)
            #pragma unroll
            for (int g = 0; g < 4; ++g) {
                const int row = m0 + wave * 32 + r * 16 + quad * 4 + g;
                if (row < NN)
                    xl[(size_t)row * HDIM + n0 + c * 16 + l15] = (_Float16)acc[r][c][g];
            }
        if (l15 == 0)
            #pragma unroll
            for (int g = 0; g < 4; ++g) {
                const int row = m0 + wave * 32 + r * 16 + quad * 4 + g;
                if (row < NN) {
                    aST[(size_t)h * NN + row] = ps[g];
                    aDT[(size_t)h * NN + row] = pd[g];
                }
            }
    }
}

// ---------------- sliced gathers (v4, frozen r9 optimum) ----------------
__device__ __forceinline__ bool slice_map3(int bid, int& s, int& m)
{
    const int r = bid & 7, k = bid >> 3;
    if (k < 625) { s = r; m = k; return true; }
    s = 8 + (r >> 2);
    m = (r & 3) * 157 + (k - 625);
    return m < 625;
}

__device__ __forceinline__ float lrexp(float a)
{
    a = (a >= 0.f) ? a : NEG * a;
    return __expf(a);
}

__global__ __launch_bounds__(256) void k_gat_gather4(
    const int* __restrict__ rowptr, const int* __restrict__ csr,
    const float* __restrict__ aST, const float* __restrict__ aDT,
    const _Float16* __restrict__ xl, const float* __restrict__ b_gat,
    _Float16* __restrict__ x1)
{
    int s, m;
    if (!slice_map3(blockIdx.x, s, m)) return;
    const int wave = threadIdx.x >> 6, lane = threadIdx.x & 63;
    const int g = lane >> 3, l = lane & 7;
    const int n = m * 32 + wave * 8 + g;
    const int col = s * 64 + l * 8;
    const float* __restrict__ as = aST + (size_t)s * NN;
    const _Float16* __restrict__ xc = xl + col;
    const float ad = aDT[(size_t)s * NN + n];

    float acc[8];
    #pragma unroll
    for (int i = 0; i < 8; ++i) acc[i] = 0.f;
    float ws = 0.f;

    const int j0 = rowptr[n], j1 = rowptr[n + 1];
    int j = j0;
    for (; j + 3 < j1; j += 4) {
        const int sA = csr[j], sB = csr[j + 1], sC = csr[j + 2], sD = csr[j + 3];
        const float wA = lrexp(as[sA] + ad);
        const float wB = lrexp(as[sB] + ad);
        const float wC = lrexp(as[sC] + ad);
        const float wD = lrexp(as[sD] + ad);
        ws += wA + wB + wC + wD;
        const half8 vA = *(const half8*)&xc[(size_t)sA * HDIM];
        const half8 vB = *(const half8*)&xc[(size_t)sB * HDIM];
        const half8 vC = *(const half8*)&xc[(size_t)sC * HDIM];
        const half8 vD = *(const half8*)&xc[(size_t)sD * HDIM];
        #pragma unroll
        for (int i = 0; i < 8; ++i) {
            acc[i] = fmaf(wA, (float)vA[i], acc[i]);
            acc[i] = fmaf(wB, (float)vB[i], acc[i]);
            acc[i] = fmaf(wC, (float)vC[i], acc[i]);
            acc[i] = fmaf(wD, (float)vD[i], acc[i]);
        }
    }
    for (; j < j1; ++j) {
        const int sA = csr[j];
        const float wA = lrexp(as[sA] + ad);
        ws += wA;
        const half8 vA = *(const half8*)&xc[(size_t)sA * HDIM];
        #pragma unroll
        for (int i = 0; i < 8; ++i) acc[i] = fmaf(wA, (float)vA[i], acc[i]);
    }

    const float rr = 1.f / (ws + 1e-16f);
    const float4 ba = *(const float4*)&b_gat[col];
    const float4 bb = *(const float4*)&b_gat[col + 4];
    const float bv[8] = {ba.x, ba.y, ba.z, ba.w, bb.x, bb.y, bb.z, bb.w};
    half8 o;
    #pragma unroll
    for (int i = 0; i < 8; ++i) {
        const float v = fmaf(acc[i], rr, bv[i]);
        o[i] = (_Float16)((v > 0.f) ? v : 0.f);
    }
    *(half8*)&x1[(size_t)n * HDIM + col] = o;
}

__global__ __launch_bounds__(256) void k_gcn_gather4(
    const int* __restrict__ rowptr, const int* __restrict__ csr,
    const float* __restrict__ dinv, const _Float16* __restrict__ x1,
    _Float16* __restrict__ t)
{
    int s, m;
    if (!slice_map3(blockIdx.x, s, m)) return;
    const int wave = threadIdx.x >> 6, lane = threadIdx.x & 63;
    const int g = lane >> 3, l = lane & 7;
    const int n = m * 32 + wave * 8 + g;
    const int col = s * 64 + l * 8;
    const _Float16* __restrict__ xc = x1 + col;
    const float dd = dinv[n];

    float acc[8];
    #pragma unroll
    for (int i = 0; i < 8; ++i) acc[i] = 0.f;

    const int j0 = rowptr[n], j1 = rowptr[n + 1];
    int j = j0;
    for (; j + 3 < j1; j += 4) {
        const int sA = csr[j], sB = csr[j + 1], sC = csr[j + 2], sD = csr[j + 3];
        const float wA = dinv[sA], wB = dinv[sB];
        const float wC = dinv[sC], wD = dinv[sD];
        const half8 vA = *(const half8*)&xc[(size_t)sA * HDIM];
        const half8 vB = *(const half8*)&xc[(size_t)sB * HDIM];
        const half8 vC = *(const half8*)&xc[(size_t)sC * HDIM];
        const half8 vD = *(const half8*)&xc[(size_t)sD * HDIM];
        #pragma unroll
        for (int i = 0; i < 8; ++i) {
            acc[i] = fmaf(wA, (float)vA[i], acc[i]);
            acc[i] = fmaf(wB, (float)vB[i], acc[i]);
            acc[i] = fmaf(wC, (float)vC[i], acc[i]);
            acc[i] = fmaf(wD, (float)vD[i], acc[i]);
        }
    }
    for (; j < j1; ++j) {
        const int sA = csr[j];
        const float wA = dinv[sA];
        const half8 vA = *(const half8*)&xc[(size_t)sA * HDIM];
        #pragma unroll
        for (int i = 0; i < 8; ++i) acc[i] = fmaf(wA, (float)vA[i], acc[i]);
    }

    half8 o;
    #pragma unroll
    for (int i = 0; i < 8; ++i) o[i] = (_Float16)(acc[i] * dd);
    *(half8*)&t[(size_t)n * HDIM + col] = o;
}

// ---------------- GEMM2 v5 (frozen r8 race-free) ----------------
__global__ __launch_bounds__(256) void k_gemm2(const _Float16* __restrict__ X,
                                               const _Float16* __restrict__ Wbt,
                                               const float* __restrict__ b_gcn,
                                               float* __restrict__ pmax,
                                               float* __restrict__ psum)
{
    __shared__ _Float16 Bs[2][128 * BKK];
    const int bid = blockIdx.x;
    const int r = bid & 7, q = bid >> 3;
    const int strip = (q / 5) * 8 + r;   // M-strip (0..156)
    const int nt = q % 5;                // N-tile (0..4)
    if (strip >= 157) return;

    const int tid = threadIdx.x;
    const int lane = tid & 63, wave = tid >> 6;
    const int l15 = lane & 15, quad = lane >> 4;
    const int m0 = strip * 128 + wave * 32;
    const int n0 = nt * 128;

    f32x4 acc[2][8];
    #pragma unroll
    for (int rr = 0; rr < 2; ++rr)
        #pragma unroll
        for (int c = 0; c < 8; ++c) acc[rr][c] = (f32x4){0.f, 0.f, 0.f, 0.f};

    const _Float16* a0p = &X[(size_t)(m0 + l15) * HDIM + quad * 8];
    const _Float16* a1p = a0p + (size_t)16 * HDIM;
    const int srow = wave * 8 + (lane >> 3);   // stage row base (0..31)
    const int sck  = lane & 7;                 // linear LDS chunk

#define STAGE4(buf, kb)                                                          \
    {                                                                            \
        _Pragma("unroll")                                                        \
        for (int i = 0; i < 4; ++i) {                                            \
            const int rw = i * 32 + srow;                                        \
            const int ck = sck ^ (rw & 7);                                       \
            const _Float16* src = &Wbt[(size_t)(n0 + rw) * HDIM + (kb) + ck * 8];\
            __builtin_amdgcn_global_load_lds(                                    \
                (const __attribute__((address_space(1))) void*)src,              \
                (__attribute__((address_space(3))) void*)&Bs[buf][((size_t)i * 256 + tid) * 8], \
                16, 0, 0);                                                       \
        }                                                                        \
    }

    STAGE4(0, 0);
    for (int it = 0; it < 10; ++it) {
        const int kb = it * BKK;
        half8 a0[2], a1[2];
        #pragma unroll
        for (int ks = 0; ks < 2; ++ks) {
            a0[ks] = *(const half8*)(a0p + kb + ks * 32);
            a1[ks] = *(const half8*)(a1p + kb + ks * 32);
        }
        if (it < 9) {
            STAGE4((it + 1) & 1, kb + BKK);
            asm volatile("s_waitcnt vmcnt(4)" ::: "memory");
        } else {
            asm volatile("s_waitcnt vmcnt(0)" ::: "memory");
        }
        __builtin_amdgcn_s_barrier();            // stage(it) visible to all waves
        __builtin_amdgcn_sched_barrier(0);       // fence: ds_reads must stay below
        const _Float16* Bsc = Bs[it & 1];
        #pragma unroll
        for (int ks = 0; ks < 2; ++ks) {
            #pragma unroll
            for (int c = 0; c < 8; ++c) {
                const int br = c * 16 + l15;
                const int ck = (ks * 4 + quad) ^ (br & 7);
                const half8 b = *(const half8*)&Bsc[(size_t)br * BKK + ck * 8];
                acc[0][c] = __builtin_amdgcn_mfma_f32_16x16x32_f16(a0[ks], b, acc[0][c], 0, 0, 0);
                acc[1][c] = __builtin_amdgcn_mfma_f32_16x16x32_f16(a1[ks], b, acc[1][c], 0, 0, 0);
            }
        }
        __builtin_amdgcn_sched_barrier(0);       // fence: ds_reads complete above
        __builtin_amdgcn_s_barrier();            // Bs[it&1] reads done before overwrite
        __builtin_amdgcn_sched_barrier(0);
    }
#undef STAGE4

    float lmax[8], lsum[8];
    #pragma unroll
    for (int c = 0; c < 8; ++c) { lmax[c] = 0.f; lsum[c] = 0.f; }
    #pragma unroll
    for (int c = 0; c < 8; ++c) {
        const float bb = b_gcn[n0 + c * 16 + l15];
        #pragma unroll
        for (int rr = 0; rr < 2; ++rr)
            #pragma unroll
            for (int g = 0; g < 4; ++g) {
                const int row = m0 + rr * 16 + quad * 4 + g;
                if (row < NN) {
                    float v = acc[rr][c][g] + bb;
                    v = (v > 0.f) ? v : 0.f;
                    lmax[c] = fmaxf(lmax[c], v);
                    lsum[c] += v;
                }
            }
    }
    float* redm = (float*)Bs;
    float* reds = redm + 128;
    if (tid < 128) { redm[tid] = 0.f; reds[tid] = 0.f; }
    __syncthreads();
    #pragma unroll
    for (int c = 0; c < 8; ++c) {
        const int col = c * 16 + l15;
        atomicMax((int*)&redm[col], __float_as_int(lmax[c]));
        atomicAdd(&reds[col], lsum[c]);
    }
    __syncthreads();
    if (tid < 128) {
        atomicMax((int*)&pmax[n0 + tid], __float_as_int(redm[tid]));
        atomicAdd(&psum[n0 + tid], reds[tid]);
    }
}

// ---------------- fused MLP: mlp1 split-K + last-block mlp2 ----------------
__global__ __launch_bounds__(256) void k_mlp(const float* __restrict__ pmax,
                                             const float* __restrict__ psum,
                                             const float* __restrict__ W1,
                                             const float* __restrict__ b1,
                                             const float* __restrict__ W2,
                                             const float* __restrict__ b2,
                                             float* __restrict__ hacc,
                                             int* __restrict__ done,
                                             float* __restrict__ out)
{
    __shared__ float pl[80];
    __shared__ int isLast;
    const int t = threadIdx.x;
    const int i0 = blockIdx.y * 80;
    if (t < 80) {
        const int i = i0 + t;
        pl[t] = (i < HDIM) ? pmax[i] : psum[i - HDIM] * (1.0f / NN);
    }
    __syncthreads();
    const int j = blockIdx.x * 256 + t;
    if (j < H1) {
        float acc = 0.f;
        #pragma unroll 8
        for (int i = 0; i < 80; ++i)
            acc = fmaf(pl[i], W1[(size_t)(i0 + i) * H1 + j], acc);
        atomicAdd(&hacc[j], acc);
    }
    __threadfence();          // release: hacc adds visible before done increment
    __syncthreads();
    if (t == 0) {
        const int total = gridDim.x * gridDim.y;
        isLast = (atomicAdd(done, 1) == total - 1) ? 1 : 0;
    }
    __syncthreads();
    if (!isLast) return;

    // last block: mlp2 (hacc read via atomic for cross-XCD coherence)
    __shared__ float hsh[H1];
    __shared__ float red[256];
    for (int i = t; i < H1; i += 256) {
        const float v = atomicAdd(&hacc[i], 0.0f) + b1[i];
        hsh[i] = (v > 0.f) ? v : 0.f;
    }
    __syncthreads();
    float acc[10];
    #pragma unroll
    for (int k = 0; k < 10; ++k) acc[k] = 0.f;
    for (int i = t; i < H1; i += 256) {
        const float h = hsh[i];
        #pragma unroll
        for (int k = 0; k < 10; ++k) acc[k] = fmaf(h, W2[i * 10 + k], acc[k]);
    }
    for (int k = 0; k < 10; ++k) {
        red[t] = acc[k]; __syncthreads();
        for (int s2 = 128; s2 > 0; s2 >>= 1) {
            if (t < s2) red[t] += red[t + s2];
            __syncthreads();
        }
        if (t == 0) out[k] = red[0] + b2[k];
        __syncthreads();
    }
}

// ---------------- launch ----------------
extern "C" void kernel_launch(void* const* d_in, const int* in_sizes, int n_in,
                              void* d_out, int out_size, void* d_ws, size_t ws_size,
                              hipStream_t stream)
{
    const float* x     = (const float*)d_in[0];
    const float* Wg    = (const float*)d_in[1];
    const float* att_s = (const float*)d_in[2];
    const float* att_d = (const float*)d_in[3];
    const float* b_gat = (const float*)d_in[4];
    const float* Wgcn  = (const float*)d_in[5];
    const float* b_gcn = (const float*)d_in[6];
    const float* W1    = (const float*)d_in[7];
    const float* b1    = (const float*)d_in[8];
    const float* W2    = (const float*)d_in[9];
    const float* b2    = (const float*)d_in[10];
    const int*   ei    = (const int*)d_in[11];
    const int E = in_sizes[11] / 2;
    const int EP = E + NN;
    float* out = (float*)d_out;

    char* wsp = (char*)d_ws;
    size_t off = 0;
    auto alc = [&](size_t b) { void* p = wsp + off; off += (b + 255) & ~(size_t)255; return p; };
    _Float16* bufA = (_Float16*)alc((size_t)NN * HDIM * 2);  // xl, later t
    _Float16* bufB = (_Float16*)alc((size_t)NN * HDIM * 2);  // x1
    float* aST    = (float*)alc((size_t)HH * NN * 4);        // [head][node]
    float* aDT    = (float*)alc((size_t)HH * NN * 4);        // [head][node]
    int*   rowptr = (int*)alc((size_t)(NN + 1) * 4);
    int*   csr    = (int*)alc((size_t)EP * 4);
    float* dinv   = (float*)alc((size_t)NN * 4);
    _Float16* Wbt = (_Float16*)alc((size_t)HDIM * HDIM * 2); // W_gcn^T fp16
    _Float16* WgT = (_Float16*)alc((size_t)HDIM * DD * 2);   // W_gat^T fp16 [640][64]
    // zero-initialized region (single memset): cnt | cursor | pmax | psum | hacc | done
    const size_t zoff = off;
    int*   cnt    = (int*)alc((size_t)NN * 4);
    int*   cursor = (int*)alc((size_t)NN * 4);
    float* pmax   = (float*)alc((size_t)HDIM * 4);
    float* psum   = (float*)alc((size_t)HDIM * 4);
    float* hacc   = (float*)alc((size_t)H1 * 4);
    int*   done   = (int*)alc(256);
    const size_t zsize = off - zoff;

    hipMemsetAsync(cnt, 0, zsize, stream);

    const int CNTB = (EP + 255) / 256;           // 1329
    k_prep<<<440 + CNTB, 256, 0, stream>>>(Wgcn, Wg, Wbt, WgT, ei, E, cnt);
    k_scan<<<1, 1024, 0, stream>>>(cnt, rowptr, dinv);
    k_big<<<1570 + CNTB, 256, 0, stream>>>(x, WgT, att_s, att_d, bufA, aST, aDT,
                                           ei, E, rowptr, cursor, csr);
    const int GG = 6256;  // 8 XCD groups x 782 (625 pinned + 157 shared)
    k_gat_gather4<<<GG, 256, 0, stream>>>(rowptr, csr, aST, aDT, bufA, b_gat, bufB);
    k_gcn_gather4<<<GG, 256, 0, stream>>>(rowptr, csr, dinv, bufB, bufA);
    k_gemm2<<<800, 256, 0, stream>>>(bufA, Wbt, b_gcn, pmax, psum);
    dim3 gm(6, 16);
    k_mlp<<<gm, 256, 0, stream>>>(pmax, psum, W1, b1, W2, b2, hacc, done, out);
}